// Round 5
// baseline (135.570 us; speedup 1.0000x reference)
//
#include <hip/hip_runtime.h>
#include <hip/hip_bf16.h>

#define KD 960
#define BT 1536   // 16*96
#define NB 16

typedef __attribute__((ext_vector_type(8))) short bf16x8;
typedef __attribute__((ext_vector_type(4))) float f32x4;

#define MFMA_16x16x32_BF16 __builtin_amdgcn_mfma_f32_16x16x32_bf16

// =============== fused prep: bf16 casts, pads, transposes ===============
__global__ __launch_bounds__(256) void prep_kernel(
    const float* __restrict__ X, const float* __restrict__ M,
    const float* __restrict__ DF, const float* __restrict__ W_e,
    const float* __restrict__ W_a, const float* __restrict__ V_a,
    __hip_bfloat16* __restrict__ inpb, __hip_bfloat16* __restrict__ Web,
    __hip_bfloat16* __restrict__ Wab, __hip_bfloat16* __restrict__ Vab,
    float* __restrict__ MT, float* __restrict__ DFT) {
    int idx = blockIdx.x * 256 + threadIdx.x;
    if (idx < 491520) {               // inp = [X,M,DF,0pad] as (BT,320) bf16
        int m = idx / 320, j = idx % 320;
        float v = 0.f;
        if (j < 96)       v = X[m * 96 + j];
        else if (j < 192) v = M[m * 96 + (j - 96)];
        else if (j < 288) v = DF[m * 96 + (j - 192)];
        inpb[idx] = __float2bfloat16(v);
        return;
    }
    idx -= 491520;
    if (idx < 307200) {               // W_e (960,288) -> (960,320) bf16
        int r = idx / 320, c = idx % 320;
        Web[idx] = __float2bfloat16(c < 288 ? W_e[r * 288 + c] : 0.f);
        return;
    }
    idx -= 307200;
    if (idx < 921600) { Wab[idx] = __float2bfloat16(W_a[idx]); return; }
    idx -= 921600;
    if (idx < 921600) { Vab[idx] = __float2bfloat16(V_a[idx]); return; }
    idx -= 921600;
    if (idx < 147456) {               // MT[b][d][t] = M[b][t][d]
        int b = idx / 9216, r = idx % 9216, d = r / 96, t = r % 96;
        MT[idx] = M[(b * 96 + t) * 96 + d];
        return;
    }
    idx -= 147456;
    if (idx < 147456) {
        int b = idx / 9216, r = idx % 9216, d = r / 96, t = r % 96;
        DFT[idx] = DF[(b * 96 + t) * 96 + d];
    }
}

// =============== MFMA staging helpers (m97 pattern, XOR-swizzled) ===============
__device__ __forceinline__ void stage64(const char* gRow0, int ldbytes,
                                        char* ldsTile, int wv, int lane) {
#pragma unroll
    for (int rd = 0; rd < 2; rd++) {
        int c  = rd * 256 + wv * 64 + lane;
        int r  = c >> 3;
        int sl = c & 7;
        int ss = sl ^ (r & 7);
        const char* g = gRow0 + (size_t)r * ldbytes + ss * 16;
        __builtin_amdgcn_global_load_lds((const void*)g,
            (void*)(ldsTile + rd * 4096 + wv * 1024), 16, 0, 0);
    }
}
__device__ __forceinline__ void stage32(const char* gRow0, int ldbytes,
                                        char* ldsTile, int tid, int wv) {
    int r  = tid >> 3;
    int sl = tid & 7;
    int ss = sl ^ (r & 7);
    const char* g = gRow0 + (size_t)r * ldbytes + ss * 16;
    __builtin_amdgcn_global_load_lds((const void*)g,
        (void*)(ldsTile + wv * 1024), 16, 0, 0);
}
__device__ __forceinline__ bf16x8 ldfrag(const char* lds, int row, int slot) {
    int ss = slot ^ (row & 7);
    return *(const bf16x8*)(lds + row * 128 + ss * 16);
}

// =============== embed: 32x64 tiles, K=320; writes heb + transposed heT ========
__global__ __launch_bounds__(256) void embed_mfma(
    const __hip_bfloat16* __restrict__ A, const __hip_bfloat16* __restrict__ Bw,
    const float* __restrict__ b_e, const float* __restrict__ pos,
    __hip_bfloat16* __restrict__ heb, __hip_bfloat16* __restrict__ heT) {
    __shared__ __align__(16) char lds[12288];
    char* As = lds; char* Bs = lds + 4096;
    int tid = threadIdx.x, lane = tid & 63, wv = tid >> 6;
    int lq = lane >> 4, lr = lane & 15;
    int m0 = blockIdx.y * 32, n0 = blockIdx.x * 64;
    int wm = (wv >> 1) * 16, wn = (wv & 1) * 32;
    f32x4 acc[2] = {};
    for (int kt = 0; kt < 5; kt++) {
        int k0b = kt * 128;
        stage32((const char*)A + (size_t)m0 * 640 + k0b, 640, As, tid, wv);
        stage64((const char*)Bw + (size_t)n0 * 640 + k0b, 640, Bs, wv, lane);
        __syncthreads();
#pragma unroll
        for (int h = 0; h < 2; h++) {
            bf16x8 a  = ldfrag(As, wm + lr, h * 4 + lq);
            bf16x8 b0 = ldfrag(Bs, wn + lr,      h * 4 + lq);
            bf16x8 b1 = ldfrag(Bs, wn + 16 + lr, h * 4 + lq);
            acc[0] = MFMA_16x16x32_BF16(a, b0, acc[0], 0, 0, 0);
            acc[1] = MFMA_16x16x32_BF16(a, b1, acc[1], 0, 0, 0);
        }
        __syncthreads();
    }
    int mbase = m0 + wm + lq * 4;
    int b = mbase / 96, t0 = mbase % 96;
#pragma unroll
    for (int ni = 0; ni < 2; ni++) {
        int n = n0 + wn + ni * 16 + lr;
        float bn = b_e[n];
        ushort4 pk;
#pragma unroll
        for (int reg = 0; reg < 4; reg++) {
            int t = t0 + reg;
            float x = acc[ni][reg] + bn + pos[t * KD + n];
            x = x > 0.f ? x : (__expf(x) - 1.f);
            __hip_bfloat16 hv = __float2bfloat16(x);
            heb[(size_t)(mbase + reg) * KD + n] = hv;
            ((unsigned short*)&pk)[reg] = *(unsigned short*)&hv;
        }
        *(ushort4*)((char*)heT + (((size_t)b * 960 + n) * 96 + t0) * 2) = pk;
    }
}

// =============== fused key/qry: K=960; key written TRANSPOSED (keyT), c2-scaled =
__global__ __launch_bounds__(256) void kq_mfma(
    const __hip_bfloat16* __restrict__ A, const __hip_bfloat16* __restrict__ B1,
    const __hip_bfloat16* __restrict__ B2,
    float* __restrict__ keyT, float* __restrict__ qryv) {
    __shared__ __align__(16) char lds[20480];
    char* As = lds; char* B1s = lds + 4096; char* B2s = lds + 12288;
    int tid = threadIdx.x, lane = tid & 63, wv = tid >> 6;
    int lq = lane >> 4, lr = lane & 15;
    int m0 = blockIdx.y * 32, n0 = blockIdx.x * 64;
    int wm = (wv >> 1) * 16, wn = (wv & 1) * 32;
    f32x4 aK[2] = {}, aQ[2] = {};
    for (int kt = 0; kt < 15; kt++) {
        int k0b = kt * 128;
        stage32((const char*)A + (size_t)m0 * 1920 + k0b, 1920, As, tid, wv);
        stage64((const char*)B1 + (size_t)n0 * 1920 + k0b, 1920, B1s, wv, lane);
        stage64((const char*)B2 + (size_t)n0 * 1920 + k0b, 1920, B2s, wv, lane);
        __syncthreads();
#pragma unroll
        for (int h = 0; h < 2; h++) {
            bf16x8 a   = ldfrag(As,  wm + lr, h * 4 + lq);
            bf16x8 b10 = ldfrag(B1s, wn + lr,      h * 4 + lq);
            bf16x8 b11 = ldfrag(B1s, wn + 16 + lr, h * 4 + lq);
            bf16x8 b20 = ldfrag(B2s, wn + lr,      h * 4 + lq);
            bf16x8 b21 = ldfrag(B2s, wn + 16 + lr, h * 4 + lq);
            aK[0] = MFMA_16x16x32_BF16(a, b10, aK[0], 0, 0, 0);
            aK[1] = MFMA_16x16x32_BF16(a, b11, aK[1], 0, 0, 0);
            aQ[0] = MFMA_16x16x32_BF16(a, b20, aQ[0], 0, 0, 0);
            aQ[1] = MFMA_16x16x32_BF16(a, b21, aQ[1], 0, 0, 0);
        }
        __syncthreads();
    }
    const float c2 = 2.885390081777927f;  // 2*log2(e)
    int mbase = m0 + wm + lq * 4;
    int bb = mbase / 96, t0 = mbase % 96;
#pragma unroll
    for (int ni = 0; ni < 2; ni++) {
        int n = n0 + wn + ni * 16 + lr;
        float4 kt4;
#pragma unroll
        for (int reg = 0; reg < 4; reg++) {
            qryv[(size_t)(mbase + reg) * KD + n] = aQ[ni][reg] * c2;
            ((float*)&kt4)[reg] = aK[ni][reg] * c2;
        }
        *(float4*)(keyT + ((size_t)bb * 960 + n) * 96 + t0) = kt4;
    }
}

// =============== attention logits + softmax -> S (bf16 probs) ==================
// lane owns (i_local, j); serial d-loop; NO cross-lane reduction.
// logit_ij = -2 * sum_d w_d * rcp(exp2(keyT_dj + qry_id) + 1)   (softmax-equiv)
__global__ __launch_bounds__(192) void attn_kernel(
    const float* __restrict__ keyT, const float* __restrict__ qry_v,
    const float* __restrict__ w_a, __hip_bfloat16* __restrict__ S) {
    __shared__ float logit_s[2][96];
    int bid = blockIdx.x;
    int b = bid & 15;            // consecutive bids -> different XCDs; b-slice stays L2-local
    int i0 = (bid >> 4) * 2;
    int tid = threadIdx.x;
    int il = tid / 96, j = tid % 96;
    const float* kp = keyT + (size_t)b * 960 * 96 + j;
    const float* qp = qry_v + ((size_t)b * 96 + i0 + il) * KD;
    float acc = 0.f;
#pragma unroll 8
    for (int d = 0; d < 960; d++) {
        float k = kp[(size_t)d * 96];
        float q = qp[d];
        float r = __builtin_amdgcn_rcpf(exp2f(k + q) + 1.f);
        acc = __builtin_fmaf(w_a[d], r, acc);
    }
    logit_s[il][j] = -2.f * acc;
    __syncthreads();

    int lane = tid & 63, wv = tid >> 6;
    if (wv < 2) {
        float x0 = logit_s[wv][lane];
        float x1 = (lane < 32) ? logit_s[wv][lane + 64] : -1e30f;
        float mx = fmaxf(x0, x1);
#pragma unroll
        for (int off = 32; off; off >>= 1) mx = fmaxf(mx, __shfl_xor(mx, off));
        float e0 = __expf(x0 - mx);
        float e1 = (lane < 32) ? __expf(x1 - mx) : 0.f;
        float sm = e0 + e1;
#pragma unroll
        for (int off = 32; off; off >>= 1) sm += __shfl_xor(sm, off);
        float inv = __fdividef(1.f, sm);
        logit_s[wv][lane] = e0 * inv;
        if (lane < 32) logit_s[wv][lane + 64] = e1 * inv;
    }
    __syncthreads();

    S[((size_t)b * 96 + i0 + il) * 96 + j] = __float2bfloat16(logit_s[il][j]);
}

// =============== h_aT = heT @ S^T  (NT-form, per-b 960x96x96), LDS-free ========
__global__ __launch_bounds__(64) void hat_mfma(
    const __hip_bfloat16* __restrict__ heT, const __hip_bfloat16* __restrict__ S,
    float* __restrict__ h_aT) {
    int b = blockIdx.x / 60;
    int d0 = (blockIdx.x % 60) * 16;
    int lane = threadIdx.x, lq = lane >> 4, lr = lane & 15;
    const char* Ab = (const char*)heT + ((size_t)b * 960 + d0) * 192;
    const char* Bb = (const char*)S + (size_t)b * 96 * 192;
    f32x4 acc[6] = {};
#pragma unroll
    for (int kt = 0; kt < 3; kt++) {
        bf16x8 a = *(const bf16x8*)(Ab + (size_t)lr * 192 + kt * 64 + lq * 16);
#pragma unroll
        for (int ni = 0; ni < 6; ni++) {
            bf16x8 bf = *(const bf16x8*)(Bb + (size_t)(ni * 16 + lr) * 192 + kt * 64 + lq * 16);
            acc[ni] = MFMA_16x16x32_BF16(a, bf, acc[ni], 0, 0, 0);
        }
    }
#pragma unroll
    for (int ni = 0; ni < 6; ni++)
#pragma unroll
        for (int reg = 0; reg < 4; reg++)
            h_aT[((size_t)b * 960 + d0 + lq * 4 + reg) * 96 + ni * 16 + lr] = acc[ni][reg];
}

// =============== temporal decay + dense-interp (fused, transposed space) =======
__global__ __launch_bounds__(128) void decayv_kernel(
    const float* __restrict__ h_aT, const float* __restrict__ MT,
    const float* __restrict__ DFT, const float* __restrict__ W_td,
    const float* __restrict__ b_td, float* __restrict__ h_rT,
    float* __restrict__ v) {
    __shared__ float red[6];
    int b = blockIdx.x / 960, kd = blockIdx.x % 960;
    int t = threadIdx.x;
    int lane = t & 63, wv = t >> 6;
    int d = kd % 96;
    float p0 = 0.f, p1 = 0.f, p2 = 0.f;
    if (t < 96) {
        const float* har = h_aT + ((size_t)b * 960 + kd) * 96;
        float ha = har[t];
        float m  = MT[((size_t)b * 96 + d) * 96 + t];
        float df = DFT[((size_t)b * 96 + d) * 96 + t];
        float g  = __expf(-fmaxf(df * W_td[kd] + b_td[kd], 0.f));
        int tsrc = t - (int)df + 1;
        float hf = har[tsrc];
        float hr = m * ha + (1.f - m) * (g * hf + (1.f - g) * ha);
        h_rT[((size_t)b * 960 + kd) * 96 + t] = hr;
        float p  = 3.f * (t + 1) * (1.f / 96.f);
        float w0 = 1.f - fabsf(p - 1.f) * (1.f / 3.f);
        float w1 = 1.f - fabsf(p - 2.f) * (1.f / 3.f);
        float w2 = 1.f - fabsf(p - 3.f) * (1.f / 3.f);
        p0 = w0 * w0 * hr; p1 = w1 * w1 * hr; p2 = w2 * w2 * hr;
    }
#pragma unroll
    for (int off = 32; off; off >>= 1) {
        p0 += __shfl_down(p0, off);
        p1 += __shfl_down(p1, off);
        p2 += __shfl_down(p2, off);
    }
    if (lane == 0) { red[wv * 3 + 0] = p0; red[wv * 3 + 1] = p1; red[wv * 3 + 2] = p2; }
    __syncthreads();
    if (t == 0) {
        float* vp = v + (size_t)b * 2880 + kd * 3;
        vp[0] = red[0] + red[3];
        vp[1] = red[1] + red[4];
        vp[2] = red[2] + red[5];
    }
}

// =============== imputation (reads h_rT coalesced, scattered write) ============
__global__ __launch_bounds__(128) void imput_kernel(
    const float* __restrict__ h_rT, const float* __restrict__ W_imp,
    const float* __restrict__ b_imp, float* __restrict__ imput) {
    int b = blockIdx.x / 96, d = blockIdx.x % 96;
    int t = threadIdx.x;
    if (t >= 96) return;
    float s = b_imp[d];
#pragma unroll
    for (int k = 0; k < 10; k++)
        s += W_imp[d * KD + k * 96 + d] * h_rT[((size_t)b * 960 + k * 96 + d) * 96 + t];
    imput[((size_t)b * 96 + t) * 96 + d] = s;
}

// =============== final FC ======================================================
__global__ __launch_bounds__(64) void fc_kernel(
    const float* __restrict__ v, const float* __restrict__ W_fc,
    const float* __restrict__ b_fc, float* __restrict__ out) {
    int b = blockIdx.x / 10, o = blockIdx.x % 10;
    int lane = threadIdx.x;
    const float* vp = v + (size_t)b * 2880;
    const float* wp = W_fc + (size_t)o * 2880;
    float s = 0.f;
    for (int j = lane; j < 2880; j += 64) s += vp[j] * wp[j];
#pragma unroll
    for (int off = 32; off; off >>= 1) s += __shfl_down(s, off);
    if (lane == 0) out[b * 10 + o] = s + b_fc[o];
}

extern "C" void kernel_launch(void* const* d_in, const int* in_sizes, int n_in,
                              void* d_out, int out_size, void* d_ws, size_t ws_size,
                              hipStream_t stream) {
    const float* X    = (const float*)d_in[0];
    const float* M    = (const float*)d_in[1];
    const float* DF   = (const float*)d_in[2];
    const float* W_e  = (const float*)d_in[3];
    const float* b_e  = (const float*)d_in[4];
    const float* pos  = (const float*)d_in[5];
    const float* W_a  = (const float*)d_in[6];
    const float* V_a  = (const float*)d_in[7];
    const float* w_a  = (const float*)d_in[8];
    const float* W_td = (const float*)d_in[9];
    const float* b_td = (const float*)d_in[10];
    const float* W_imp= (const float*)d_in[11];
    const float* b_imp= (const float*)d_in[12];
    const float* W_fc = (const float*)d_in[13];
    const float* b_fc = (const float*)d_in[14];

    float* out   = (float*)d_out;         // (16,10)
    float* imput = (float*)d_out + 160;   // (16,96,96)

    char* w = (char*)d_ws;
    __hip_bfloat16* inpb = (__hip_bfloat16*)(w);             //   983,040
    __hip_bfloat16* Web  = (__hip_bfloat16*)(w + 983040);    //   614,400
    __hip_bfloat16* Wab  = (__hip_bfloat16*)(w + 1597440);   // 1,843,200
    __hip_bfloat16* Vab  = (__hip_bfloat16*)(w + 3440640);   // 1,843,200
    __hip_bfloat16* heb  = (__hip_bfloat16*)(w + 5283840);   // 2,949,120
    __hip_bfloat16* heT  = (__hip_bfloat16*)(w + 8232960);   // 2,949,120
    __hip_bfloat16* Sp   = (__hip_bfloat16*)(w + 11182080);  //   294,912
    float* MT   = (float*)(w + 11476992);                    //   589,824
    float* DFT  = (float*)(w + 12066816);                    //   589,824
    float* keyT = (float*)(w + 12656640);                    // 5,898,240  [16][960][96]
    float* qryv = (float*)(w + 18554880);                    // 5,898,240
    float* h_aT = keyT;   // keyT dead after attn
    float* h_rT = qryv;   // qryv dead after attn
    float* vv   = (float*)(w + 24453120);                    //   184,320

    prep_kernel<<<11472, 256, 0, stream>>>(X, M, DF, W_e, W_a, V_a,
                                           inpb, Web, Wab, Vab, MT, DFT);
    embed_mfma<<<dim3(15, 48), 256, 0, stream>>>(inpb, Web, b_e, pos, heb, heT);
    kq_mfma<<<dim3(15, 48), 256, 0, stream>>>(heb, Wab, Vab, keyT, qryv);
    attn_kernel<<<NB * 48, 192, 0, stream>>>(keyT, qryv, w_a, Sp);
    hat_mfma<<<NB * 60, 64, 0, stream>>>(heT, Sp, h_aT);
    decayv_kernel<<<NB * 960, 128, 0, stream>>>(h_aT, MT, DFT, W_td, b_td, h_rT, vv);
    imput_kernel<<<NB * 96, 128, 0, stream>>>(h_rT, W_imp, b_imp, imput);
    fc_kernel<<<160, 64, 0, stream>>>(vv, W_fc, b_fc, out);
}

// Round 6
// 119.600 us; speedup vs baseline: 1.1335x; 1.1335x over previous
//
#include <hip/hip_runtime.h>
#include <hip/hip_bf16.h>

#define KD 960
#define BT 1536   // 16*96
#define NB 16

typedef __attribute__((ext_vector_type(8))) short bf16x8;
typedef __attribute__((ext_vector_type(4))) float f32x4;

#define MFMA_16x16x32_BF16 __builtin_amdgcn_mfma_f32_16x16x32_bf16

// =============== fused prep: bf16 casts, pads, transposes ===============
__global__ __launch_bounds__(256) void prep_kernel(
    const float* __restrict__ X, const float* __restrict__ M,
    const float* __restrict__ DF, const float* __restrict__ W_e,
    const float* __restrict__ W_a, const float* __restrict__ V_a,
    __hip_bfloat16* __restrict__ inpb, __hip_bfloat16* __restrict__ Web,
    __hip_bfloat16* __restrict__ Wab, __hip_bfloat16* __restrict__ Vab,
    float* __restrict__ MT, float* __restrict__ DFT) {
    int idx = blockIdx.x * 256 + threadIdx.x;
    if (idx < 491520) {               // inp = [X,M,DF,0pad] as (BT,320) bf16
        int m = idx / 320, j = idx % 320;
        float v = 0.f;
        if (j < 96)       v = X[m * 96 + j];
        else if (j < 192) v = M[m * 96 + (j - 96)];
        else if (j < 288) v = DF[m * 96 + (j - 192)];
        inpb[idx] = __float2bfloat16(v);
        return;
    }
    idx -= 491520;
    if (idx < 307200) {               // W_e (960,288) -> (960,320) bf16
        int r = idx / 320, c = idx % 320;
        Web[idx] = __float2bfloat16(c < 288 ? W_e[r * 288 + c] : 0.f);
        return;
    }
    idx -= 307200;
    if (idx < 921600) { Wab[idx] = __float2bfloat16(W_a[idx]); return; }
    idx -= 921600;
    if (idx < 921600) { Vab[idx] = __float2bfloat16(V_a[idx]); return; }
    idx -= 921600;
    if (idx < 147456) {               // MT[b][d][t] = M[b][t][d]
        int b = idx / 9216, r = idx % 9216, d = r / 96, t = r % 96;
        MT[idx] = M[(b * 96 + t) * 96 + d];
        return;
    }
    idx -= 147456;
    if (idx < 147456) {
        int b = idx / 9216, r = idx % 9216, d = r / 96, t = r % 96;
        DFT[idx] = DF[(b * 96 + t) * 96 + d];
    }
}

// =============== MFMA staging helpers (m97 pattern, XOR-swizzled) ===============
__device__ __forceinline__ void stage64(const char* gRow0, int ldbytes,
                                        char* ldsTile, int wv, int lane) {
#pragma unroll
    for (int rd = 0; rd < 2; rd++) {
        int c  = rd * 256 + wv * 64 + lane;
        int r  = c >> 3;
        int sl = c & 7;
        int ss = sl ^ (r & 7);
        const char* g = gRow0 + (size_t)r * ldbytes + ss * 16;
        __builtin_amdgcn_global_load_lds((const void*)g,
            (void*)(ldsTile + rd * 4096 + wv * 1024), 16, 0, 0);
    }
}
__device__ __forceinline__ void stage32(const char* gRow0, int ldbytes,
                                        char* ldsTile, int tid, int wv) {
    int r  = tid >> 3;
    int sl = tid & 7;
    int ss = sl ^ (r & 7);
    const char* g = gRow0 + (size_t)r * ldbytes + ss * 16;
    __builtin_amdgcn_global_load_lds((const void*)g,
        (void*)(ldsTile + wv * 1024), 16, 0, 0);
}
__device__ __forceinline__ bf16x8 ldfrag(const char* lds, int row, int slot) {
    int ss = slot ^ (row & 7);
    return *(const bf16x8*)(lds + row * 128 + ss * 16);
}

// =============== embed: 32x64 tiles, K=320; writes heb + transposed heT ========
__global__ __launch_bounds__(256) void embed_mfma(
    const __hip_bfloat16* __restrict__ A, const __hip_bfloat16* __restrict__ Bw,
    const float* __restrict__ b_e, const float* __restrict__ pos,
    __hip_bfloat16* __restrict__ heb, __hip_bfloat16* __restrict__ heT) {
    __shared__ __align__(16) char lds[12288];
    char* As = lds; char* Bs = lds + 4096;
    int tid = threadIdx.x, lane = tid & 63, wv = tid >> 6;
    int lq = lane >> 4, lr = lane & 15;
    int m0 = blockIdx.y * 32, n0 = blockIdx.x * 64;
    int wm = (wv >> 1) * 16, wn = (wv & 1) * 32;
    f32x4 acc[2] = {};
    for (int kt = 0; kt < 5; kt++) {
        int k0b = kt * 128;
        stage32((const char*)A + (size_t)m0 * 640 + k0b, 640, As, tid, wv);
        stage64((const char*)Bw + (size_t)n0 * 640 + k0b, 640, Bs, wv, lane);
        __syncthreads();
#pragma unroll
        for (int h = 0; h < 2; h++) {
            bf16x8 a  = ldfrag(As, wm + lr, h * 4 + lq);
            bf16x8 b0 = ldfrag(Bs, wn + lr,      h * 4 + lq);
            bf16x8 b1 = ldfrag(Bs, wn + 16 + lr, h * 4 + lq);
            acc[0] = MFMA_16x16x32_BF16(a, b0, acc[0], 0, 0, 0);
            acc[1] = MFMA_16x16x32_BF16(a, b1, acc[1], 0, 0, 0);
        }
        __syncthreads();
    }
    int mbase = m0 + wm + lq * 4;
    int b = mbase / 96, t0 = mbase % 96;
#pragma unroll
    for (int ni = 0; ni < 2; ni++) {
        int n = n0 + wn + ni * 16 + lr;
        float bn = b_e[n];
        ushort4 pk;
#pragma unroll
        for (int reg = 0; reg < 4; reg++) {
            int t = t0 + reg;
            float x = acc[ni][reg] + bn + pos[t * KD + n];
            x = x > 0.f ? x : (__expf(x) - 1.f);
            __hip_bfloat16 hv = __float2bfloat16(x);
            heb[(size_t)(mbase + reg) * KD + n] = hv;
            ((unsigned short*)&pk)[reg] = *(unsigned short*)&hv;
        }
        *(ushort4*)((char*)heT + (((size_t)b * 960 + n) * 96 + t0) * 2) = pk;
    }
}

// =============== fused key/qry GEMM; epilogue stores EK=e^{2k}, EQ=e^{2q} ======
__global__ __launch_bounds__(256) void kq_mfma(
    const __hip_bfloat16* __restrict__ A, const __hip_bfloat16* __restrict__ B1,
    const __hip_bfloat16* __restrict__ B2,
    float* __restrict__ EK, float* __restrict__ EQ) {
    __shared__ __align__(16) char lds[20480];
    char* As = lds; char* B1s = lds + 4096; char* B2s = lds + 12288;
    int tid = threadIdx.x, lane = tid & 63, wv = tid >> 6;
    int lq = lane >> 4, lr = lane & 15;
    int m0 = blockIdx.y * 32, n0 = blockIdx.x * 64;
    int wm = (wv >> 1) * 16, wn = (wv & 1) * 32;
    f32x4 aK[2] = {}, aQ[2] = {};
    for (int kt = 0; kt < 15; kt++) {
        int k0b = kt * 128;
        stage32((const char*)A + (size_t)m0 * 1920 + k0b, 1920, As, tid, wv);
        stage64((const char*)B1 + (size_t)n0 * 1920 + k0b, 1920, B1s, wv, lane);
        stage64((const char*)B2 + (size_t)n0 * 1920 + k0b, 1920, B2s, wv, lane);
        __syncthreads();
#pragma unroll
        for (int h = 0; h < 2; h++) {
            bf16x8 a   = ldfrag(As,  wm + lr, h * 4 + lq);
            bf16x8 b10 = ldfrag(B1s, wn + lr,      h * 4 + lq);
            bf16x8 b11 = ldfrag(B1s, wn + 16 + lr, h * 4 + lq);
            bf16x8 b20 = ldfrag(B2s, wn + lr,      h * 4 + lq);
            bf16x8 b21 = ldfrag(B2s, wn + 16 + lr, h * 4 + lq);
            aK[0] = MFMA_16x16x32_BF16(a, b10, aK[0], 0, 0, 0);
            aK[1] = MFMA_16x16x32_BF16(a, b11, aK[1], 0, 0, 0);
            aQ[0] = MFMA_16x16x32_BF16(a, b20, aQ[0], 0, 0, 0);
            aQ[1] = MFMA_16x16x32_BF16(a, b21, aQ[1], 0, 0, 0);
        }
        __syncthreads();
    }
    const float c2 = 2.885390081777927f;  // 2*log2(e)
    int mbase = m0 + wm + lq * 4;
#pragma unroll
    for (int ni = 0; ni < 2; ni++) {
        int n = n0 + wn + ni * 16 + lr;
#pragma unroll
        for (int reg = 0; reg < 4; reg++) {
            float ek = exp2f(fminf(fmaxf(aK[ni][reg] * c2, -80.f), 80.f));
            float eq = exp2f(fminf(fmaxf(aQ[ni][reg] * c2, -80.f), 80.f));
            EK[(size_t)(mbase + reg) * KD + n] = ek;
            EQ[(size_t)(mbase + reg) * KD + n] = eq;
        }
    }
}

// =============== attention logits + softmax -> S (bf16 probs) ==================
// tanh(k+q) = 1 - 2*rcp(EK*EQ+1);  logit = -2*sum_d w_d*rcp(EK_jd*EQ_id+1)
// block: (b, 4 i-rows); 384 thr = j(96) x dq(4); d-quarters combined via LDS.
__global__ __launch_bounds__(384) void attn_kernel(
    const float* __restrict__ EK, const float* __restrict__ EQ,
    const float* __restrict__ w_a, __hip_bfloat16* __restrict__ S) {
    __shared__ float part[4][4][96];
    __shared__ float logit_s[4][96];
    int bid = blockIdx.x;
    int b = bid & 15, i0 = (bid >> 4) * 4;
    int tid = threadIdx.x;
    int j = tid % 96, dq = tid / 96;       // dq in 0..3
    const float* ekp = EK + ((size_t)b * 96 + j) * KD + dq * 240;
    const float* eqp = EQ + ((size_t)b * 96 + i0) * KD + dq * 240;
    const float* wp  = w_a + dq * 240;
    float a0 = 0.f, a1 = 0.f, a2 = 0.f, a3 = 0.f;
#pragma unroll 2
    for (int dd = 0; dd < 240; dd += 4) {
        float4 ek = *(const float4*)(ekp + dd);
        float4 q0 = *(const float4*)(eqp + dd);
        float4 q1 = *(const float4*)(eqp + KD + dd);
        float4 q2 = *(const float4*)(eqp + 2 * KD + dd);
        float4 q3 = *(const float4*)(eqp + 3 * KD + dd);
        float4 w4 = *(const float4*)(wp + dd);
#pragma unroll
        for (int c = 0; c < 4; c++) {
            float ekc = ((const float*)&ek)[c];
            float wc  = ((const float*)&w4)[c];
            float r0 = __builtin_amdgcn_rcpf(__builtin_fmaf(ekc, ((const float*)&q0)[c], 1.f));
            float r1 = __builtin_amdgcn_rcpf(__builtin_fmaf(ekc, ((const float*)&q1)[c], 1.f));
            float r2 = __builtin_amdgcn_rcpf(__builtin_fmaf(ekc, ((const float*)&q2)[c], 1.f));
            float r3 = __builtin_amdgcn_rcpf(__builtin_fmaf(ekc, ((const float*)&q3)[c], 1.f));
            a0 = __builtin_fmaf(wc, r0, a0);
            a1 = __builtin_fmaf(wc, r1, a1);
            a2 = __builtin_fmaf(wc, r2, a2);
            a3 = __builtin_fmaf(wc, r3, a3);
        }
    }
    part[dq][0][j] = a0; part[dq][1][j] = a1;
    part[dq][2][j] = a2; part[dq][3][j] = a3;
    __syncthreads();

    int i = tid / 96;   // reuse 384 threads as (i, j)
    float lsum = part[0][i][j] + part[1][i][j] + part[2][i][j] + part[3][i][j];
    logit_s[i][j] = -2.f * lsum;
    __syncthreads();

    int lane = tid & 63, wv = tid >> 6;
    if (wv < 4) {
        float x0 = logit_s[wv][lane];
        float x1 = (lane < 32) ? logit_s[wv][lane + 64] : -1e30f;
        float mx = fmaxf(x0, x1);
#pragma unroll
        for (int off = 32; off; off >>= 1) mx = fmaxf(mx, __shfl_xor(mx, off));
        float e0 = __expf(x0 - mx);
        float e1 = (lane < 32) ? __expf(x1 - mx) : 0.f;
        float sm = e0 + e1;
#pragma unroll
        for (int off = 32; off; off >>= 1) sm += __shfl_xor(sm, off);
        float inv = __fdividef(1.f, sm);
        logit_s[wv][lane] = e0 * inv;
        if (lane < 32) logit_s[wv][lane + 64] = e1 * inv;
    }
    __syncthreads();

    S[((size_t)b * 96 + i0 + i) * 96 + j] = __float2bfloat16(logit_s[i][j]);
}

// =============== h_aT = heT @ S^T  (NT-form, per-b 960x96x96), LDS-free ========
__global__ __launch_bounds__(64) void hat_mfma(
    const __hip_bfloat16* __restrict__ heT, const __hip_bfloat16* __restrict__ S,
    float* __restrict__ h_aT) {
    int b = blockIdx.x / 60;
    int d0 = (blockIdx.x % 60) * 16;
    int lane = threadIdx.x, lq = lane >> 4, lr = lane & 15;
    const char* Ab = (const char*)heT + ((size_t)b * 960 + d0) * 192;
    const char* Bb = (const char*)S + (size_t)b * 96 * 192;
    f32x4 acc[6] = {};
#pragma unroll
    for (int kt = 0; kt < 3; kt++) {
        bf16x8 a = *(const bf16x8*)(Ab + (size_t)lr * 192 + kt * 64 + lq * 16);
#pragma unroll
        for (int ni = 0; ni < 6; ni++) {
            bf16x8 bf = *(const bf16x8*)(Bb + (size_t)(ni * 16 + lr) * 192 + kt * 64 + lq * 16);
            acc[ni] = MFMA_16x16x32_BF16(a, bf, acc[ni], 0, 0, 0);
        }
    }
#pragma unroll
    for (int ni = 0; ni < 6; ni++)
#pragma unroll
        for (int reg = 0; reg < 4; reg++)
            h_aT[((size_t)b * 960 + d0 + lq * 4 + reg) * 96 + ni * 16 + lr] = acc[ni][reg];
}

// =============== temporal decay + dense-interp (fused, transposed space) =======
__global__ __launch_bounds__(128) void decayv_kernel(
    const float* __restrict__ h_aT, const float* __restrict__ MT,
    const float* __restrict__ DFT, const float* __restrict__ W_td,
    const float* __restrict__ b_td, float* __restrict__ h_rT,
    float* __restrict__ v) {
    __shared__ float red[6];
    int b = blockIdx.x / 960, kd = blockIdx.x % 960;
    int t = threadIdx.x;
    int lane = t & 63, wv = t >> 6;
    int d = kd % 96;
    float p0 = 0.f, p1 = 0.f, p2 = 0.f;
    if (t < 96) {
        const float* har = h_aT + ((size_t)b * 960 + kd) * 96;
        float ha = har[t];
        float m  = MT[((size_t)b * 96 + d) * 96 + t];
        float df = DFT[((size_t)b * 96 + d) * 96 + t];
        float g  = __expf(-fmaxf(df * W_td[kd] + b_td[kd], 0.f));
        int tsrc = t - (int)df + 1;
        float hf = har[tsrc];
        float hr = m * ha + (1.f - m) * (g * hf + (1.f - g) * ha);
        h_rT[((size_t)b * 960 + kd) * 96 + t] = hr;
        float p  = 3.f * (t + 1) * (1.f / 96.f);
        float w0 = 1.f - fabsf(p - 1.f) * (1.f / 3.f);
        float w1 = 1.f - fabsf(p - 2.f) * (1.f / 3.f);
        float w2 = 1.f - fabsf(p - 3.f) * (1.f / 3.f);
        p0 = w0 * w0 * hr; p1 = w1 * w1 * hr; p2 = w2 * w2 * hr;
    }
#pragma unroll
    for (int off = 32; off; off >>= 1) {
        p0 += __shfl_down(p0, off);
        p1 += __shfl_down(p1, off);
        p2 += __shfl_down(p2, off);
    }
    if (lane == 0) { red[wv * 3 + 0] = p0; red[wv * 3 + 1] = p1; red[wv * 3 + 2] = p2; }
    __syncthreads();
    if (t == 0) {
        float* vp = v + (size_t)b * 2880 + kd * 3;
        vp[0] = red[0] + red[3];
        vp[1] = red[1] + red[4];
        vp[2] = red[2] + red[5];
    }
}

// =============== imputation (reads h_rT coalesced, scattered write) ============
__global__ __launch_bounds__(128) void imput_kernel(
    const float* __restrict__ h_rT, const float* __restrict__ W_imp,
    const float* __restrict__ b_imp, float* __restrict__ imput) {
    int b = blockIdx.x / 96, d = blockIdx.x % 96;
    int t = threadIdx.x;
    if (t >= 96) return;
    float s = b_imp[d];
#pragma unroll
    for (int k = 0; k < 10; k++)
        s += W_imp[d * KD + k * 96 + d] * h_rT[((size_t)b * 960 + k * 96 + d) * 96 + t];
    imput[((size_t)b * 96 + t) * 96 + d] = s;
}

// =============== final FC ======================================================
__global__ __launch_bounds__(64) void fc_kernel(
    const float* __restrict__ v, const float* __restrict__ W_fc,
    const float* __restrict__ b_fc, float* __restrict__ out) {
    int b = blockIdx.x / 10, o = blockIdx.x % 10;
    int lane = threadIdx.x;
    const float* vp = v + (size_t)b * 2880;
    const float* wp = W_fc + (size_t)o * 2880;
    float s = 0.f;
    for (int j = lane; j < 2880; j += 64) s += vp[j] * wp[j];
#pragma unroll
    for (int off = 32; off; off >>= 1) s += __shfl_down(s, off);
    if (lane == 0) out[b * 10 + o] = s + b_fc[o];
}

extern "C" void kernel_launch(void* const* d_in, const int* in_sizes, int n_in,
                              void* d_out, int out_size, void* d_ws, size_t ws_size,
                              hipStream_t stream) {
    const float* X    = (const float*)d_in[0];
    const float* M    = (const float*)d_in[1];
    const float* DF   = (const float*)d_in[2];
    const float* W_e  = (const float*)d_in[3];
    const float* b_e  = (const float*)d_in[4];
    const float* pos  = (const float*)d_in[5];
    const float* W_a  = (const float*)d_in[6];
    const float* V_a  = (const float*)d_in[7];
    const float* w_a  = (const float*)d_in[8];
    const float* W_td = (const float*)d_in[9];
    const float* b_td = (const float*)d_in[10];
    const float* W_imp= (const float*)d_in[11];
    const float* b_imp= (const float*)d_in[12];
    const float* W_fc = (const float*)d_in[13];
    const float* b_fc = (const float*)d_in[14];

    float* out   = (float*)d_out;         // (16,10)
    float* imput = (float*)d_out + 160;   // (16,96,96)

    char* w = (char*)d_ws;
    __hip_bfloat16* inpb = (__hip_bfloat16*)(w);             //   983,040
    __hip_bfloat16* Web  = (__hip_bfloat16*)(w + 983040);    //   614,400
    __hip_bfloat16* Wab  = (__hip_bfloat16*)(w + 1597440);   // 1,843,200
    __hip_bfloat16* Vab  = (__hip_bfloat16*)(w + 3440640);   // 1,843,200
    __hip_bfloat16* heb  = (__hip_bfloat16*)(w + 5283840);   // 2,949,120
    __hip_bfloat16* heT  = (__hip_bfloat16*)(w + 8232960);   // 2,949,120
    __hip_bfloat16* Sp   = (__hip_bfloat16*)(w + 11182080);  //   294,912
    float* MT   = (float*)(w + 11476992);                    //   589,824
    float* DFT  = (float*)(w + 12066816);                    //   589,824
    float* EK   = (float*)(w + 12656640);                    // 5,898,240
    float* EQ   = (float*)(w + 18554880);                    // 5,898,240
    float* h_aT = EK;    // EK dead after attn
    float* h_rT = EQ;    // EQ dead after attn
    float* vv   = (float*)(w + 24453120);                    //   184,320

    prep_kernel<<<11472, 256, 0, stream>>>(X, M, DF, W_e, W_a, V_a,
                                           inpb, Web, Wab, Vab, MT, DFT);
    embed_mfma<<<dim3(15, 48), 256, 0, stream>>>(inpb, Web, b_e, pos, heb, heT);
    kq_mfma<<<dim3(15, 48), 256, 0, stream>>>(heb, Wab, Vab, EK, EQ);
    attn_kernel<<<NB * 24, 384, 0, stream>>>(EK, EQ, w_a, Sp);
    hat_mfma<<<NB * 60, 64, 0, stream>>>(heT, Sp, h_aT);
    decayv_kernel<<<NB * 960, 128, 0, stream>>>(h_aT, MT, DFT, W_td, b_td, h_rT, vv);
    imput_kernel<<<NB * 96, 128, 0, stream>>>(h_rT, W_imp, b_imp, imput);
    fc_kernel<<<160, 64, 0, stream>>>(vv, W_fc, b_fc, out);
}

// Round 7
// 99.156 us; speedup vs baseline: 1.3672x; 1.2062x over previous
//
#include <hip/hip_runtime.h>
#include <hip/hip_bf16.h>

#define KD 960
#define BT 1536   // 16*96
#define NB 16

typedef __attribute__((ext_vector_type(8))) short bf16x8;
typedef __attribute__((ext_vector_type(4))) float f32x4;

#define MFMA_16x16x32_BF16 __builtin_amdgcn_mfma_f32_16x16x32_bf16

// =============== fused prep: bf16 casts, pads, transposes ===============
__global__ __launch_bounds__(256) void prep_kernel(
    const float* __restrict__ X, const float* __restrict__ M,
    const float* __restrict__ DF, const float* __restrict__ W_e,
    const float* __restrict__ W_a, const float* __restrict__ V_a,
    __hip_bfloat16* __restrict__ inpb, __hip_bfloat16* __restrict__ Web,
    __hip_bfloat16* __restrict__ Wab, __hip_bfloat16* __restrict__ Vab,
    float* __restrict__ MT, float* __restrict__ DFT) {
    int idx = blockIdx.x * 256 + threadIdx.x;
    if (idx < 491520) {               // inp = [X,M,DF,0pad] as (BT,320) bf16
        int m = idx / 320, j = idx % 320;
        float v = 0.f;
        if (j < 96)       v = X[m * 96 + j];
        else if (j < 192) v = M[m * 96 + (j - 96)];
        else if (j < 288) v = DF[m * 96 + (j - 192)];
        inpb[idx] = __float2bfloat16(v);
        return;
    }
    idx -= 491520;
    if (idx < 307200) {               // W_e (960,288) -> (960,320) bf16
        int r = idx / 320, c = idx % 320;
        Web[idx] = __float2bfloat16(c < 288 ? W_e[r * 288 + c] : 0.f);
        return;
    }
    idx -= 307200;
    if (idx < 921600) { Wab[idx] = __float2bfloat16(W_a[idx]); return; }
    idx -= 921600;
    if (idx < 921600) { Vab[idx] = __float2bfloat16(V_a[idx]); return; }
    idx -= 921600;
    if (idx < 147456) {               // MT[b][d][t] = M[b][t][d]
        int b = idx / 9216, r = idx % 9216, d = r / 96, t = r % 96;
        MT[idx] = M[(b * 96 + t) * 96 + d];
        return;
    }
    idx -= 147456;
    if (idx < 147456) {
        int b = idx / 9216, r = idx % 9216, d = r / 96, t = r % 96;
        DFT[idx] = DF[(b * 96 + t) * 96 + d];
    }
}

// =============== MFMA staging helpers (m97 pattern, XOR-swizzled) ===============
__device__ __forceinline__ void stage64(const char* gRow0, int ldbytes,
                                        char* ldsTile, int wv, int lane) {
#pragma unroll
    for (int rd = 0; rd < 2; rd++) {
        int c  = rd * 256 + wv * 64 + lane;
        int r  = c >> 3;
        int sl = c & 7;
        int ss = sl ^ (r & 7);
        const char* g = gRow0 + (size_t)r * ldbytes + ss * 16;
        __builtin_amdgcn_global_load_lds((const void*)g,
            (void*)(ldsTile + rd * 4096 + wv * 1024), 16, 0, 0);
    }
}
__device__ __forceinline__ void stage32(const char* gRow0, int ldbytes,
                                        char* ldsTile, int tid, int wv) {
    int r  = tid >> 3;
    int sl = tid & 7;
    int ss = sl ^ (r & 7);
    const char* g = gRow0 + (size_t)r * ldbytes + ss * 16;
    __builtin_amdgcn_global_load_lds((const void*)g,
        (void*)(ldsTile + wv * 1024), 16, 0, 0);
}
__device__ __forceinline__ bf16x8 ldfrag(const char* lds, int row, int slot) {
    int ss = slot ^ (row & 7);
    return *(const bf16x8*)(lds + row * 128 + ss * 16);
}

// =============== embed: 32x64 tiles, K=320; writes heb + transposed heT ========
__global__ __launch_bounds__(256) void embed_mfma(
    const __hip_bfloat16* __restrict__ A, const __hip_bfloat16* __restrict__ Bw,
    const float* __restrict__ b_e, const float* __restrict__ pos,
    __hip_bfloat16* __restrict__ heb, __hip_bfloat16* __restrict__ heT) {
    __shared__ __align__(16) char lds[12288];
    char* As = lds; char* Bs = lds + 4096;
    int tid = threadIdx.x, lane = tid & 63, wv = tid >> 6;
    int lq = lane >> 4, lr = lane & 15;
    int m0 = blockIdx.y * 32, n0 = blockIdx.x * 64;
    int wm = (wv >> 1) * 16, wn = (wv & 1) * 32;
    f32x4 acc[2] = {};
    for (int kt = 0; kt < 5; kt++) {
        int k0b = kt * 128;
        stage32((const char*)A + (size_t)m0 * 640 + k0b, 640, As, tid, wv);
        stage64((const char*)Bw + (size_t)n0 * 640 + k0b, 640, Bs, wv, lane);
        __syncthreads();
#pragma unroll
        for (int h = 0; h < 2; h++) {
            bf16x8 a  = ldfrag(As, wm + lr, h * 4 + lq);
            bf16x8 b0 = ldfrag(Bs, wn + lr,      h * 4 + lq);
            bf16x8 b1 = ldfrag(Bs, wn + 16 + lr, h * 4 + lq);
            acc[0] = MFMA_16x16x32_BF16(a, b0, acc[0], 0, 0, 0);
            acc[1] = MFMA_16x16x32_BF16(a, b1, acc[1], 0, 0, 0);
        }
        __syncthreads();
    }
    int mbase = m0 + wm + lq * 4;
    int b = mbase / 96, t0 = mbase % 96;
#pragma unroll
    for (int ni = 0; ni < 2; ni++) {
        int n = n0 + wn + ni * 16 + lr;
        float bn = b_e[n];
        ushort4 pk;
#pragma unroll
        for (int reg = 0; reg < 4; reg++) {
            int t = t0 + reg;
            float x = acc[ni][reg] + bn + pos[t * KD + n];
            x = x > 0.f ? x : (__expf(x) - 1.f);
            __hip_bfloat16 hv = __float2bfloat16(x);
            heb[(size_t)(mbase + reg) * KD + n] = hv;
            ((unsigned short*)&pk)[reg] = *(unsigned short*)&hv;
        }
        *(ushort4*)((char*)heT + (((size_t)b * 960 + n) * 96 + t0) * 2) = pk;
    }
}

// =============== fused key/qry GEMM; epilogue stores EK=e^{2k}, EQ=e^{2q} ======
__global__ __launch_bounds__(256) void kq_mfma(
    const __hip_bfloat16* __restrict__ A, const __hip_bfloat16* __restrict__ B1,
    const __hip_bfloat16* __restrict__ B2,
    float* __restrict__ EK, float* __restrict__ EQ) {
    __shared__ __align__(16) char lds[20480];
    char* As = lds; char* B1s = lds + 4096; char* B2s = lds + 12288;
    int tid = threadIdx.x, lane = tid & 63, wv = tid >> 6;
    int lq = lane >> 4, lr = lane & 15;
    int m0 = blockIdx.y * 32, n0 = blockIdx.x * 64;
    int wm = (wv >> 1) * 16, wn = (wv & 1) * 32;
    f32x4 aK[2] = {}, aQ[2] = {};
    for (int kt = 0; kt < 15; kt++) {
        int k0b = kt * 128;
        stage32((const char*)A + (size_t)m0 * 1920 + k0b, 1920, As, tid, wv);
        stage64((const char*)B1 + (size_t)n0 * 1920 + k0b, 1920, B1s, wv, lane);
        stage64((const char*)B2 + (size_t)n0 * 1920 + k0b, 1920, B2s, wv, lane);
        __syncthreads();
#pragma unroll
        for (int h = 0; h < 2; h++) {
            bf16x8 a   = ldfrag(As,  wm + lr, h * 4 + lq);
            bf16x8 b10 = ldfrag(B1s, wn + lr,      h * 4 + lq);
            bf16x8 b11 = ldfrag(B1s, wn + 16 + lr, h * 4 + lq);
            bf16x8 b20 = ldfrag(B2s, wn + lr,      h * 4 + lq);
            bf16x8 b21 = ldfrag(B2s, wn + 16 + lr, h * 4 + lq);
            aK[0] = MFMA_16x16x32_BF16(a, b10, aK[0], 0, 0, 0);
            aK[1] = MFMA_16x16x32_BF16(a, b11, aK[1], 0, 0, 0);
            aQ[0] = MFMA_16x16x32_BF16(a, b20, aQ[0], 0, 0, 0);
            aQ[1] = MFMA_16x16x32_BF16(a, b21, aQ[1], 0, 0, 0);
        }
        __syncthreads();
    }
    const float c2 = 2.885390081777927f;  // 2*log2(e)
    int mbase = m0 + wm + lq * 4;
#pragma unroll
    for (int ni = 0; ni < 2; ni++) {
        int n = n0 + wn + ni * 16 + lr;
#pragma unroll
        for (int reg = 0; reg < 4; reg++) {
            float ek = exp2f(fminf(fmaxf(aK[ni][reg] * c2, -80.f), 80.f));
            float eq = exp2f(fminf(fmaxf(aQ[ni][reg] * c2, -80.f), 80.f));
            EK[(size_t)(mbase + reg) * KD + n] = ek;
            EQ[(size_t)(mbase + reg) * KD + n] = eq;
        }
    }
}

// =============== attention logits + softmax -> S (bf16 probs) ==================
// logit = -2*sum_d w_d*rcp(EK_jd*EQ_id+1)   (softmax-equiv; tanh factored)
// block (b, 4 i-rows), 512 thr = 8 waves; wave owns j = wv+8k (12 iters);
// lane owns fixed float4 d-slices (4 chunks of 240; lanes 60-63 masked w=0).
// EK loads coalesced (16B/lane); EQ/w register-resident; butterfly reduce.
__global__ __launch_bounds__(512) void attn_kernel(
    const float* __restrict__ EK, const float* __restrict__ EQ,
    const float* __restrict__ w_a, __hip_bfloat16* __restrict__ S) {
    __shared__ float logit_s[4][96];
    int bid = blockIdx.x;
    int b = bid & 15, i0 = (bid >> 4) * 4;   // bid&7 = XCD: each XCD owns 2 b-slices
    int tid = threadIdx.x;
    int lane = tid & 63, wv = tid >> 6;
    bool act = lane < 60;

    int col[4];
    float4 w4[4], eq[4][4];
#pragma unroll
    for (int s = 0; s < 4; s++) {
        col[s] = act ? s * 240 + lane * 4 : 0;
        if (act) w4[s] = *(const float4*)(w_a + s * 240 + lane * 4);
        else     w4[s] = float4{0.f, 0.f, 0.f, 0.f};
#pragma unroll
        for (int i = 0; i < 4; i++)
            eq[s][i] = *(const float4*)(EQ + ((size_t)b * 96 + i0 + i) * KD + col[s]);
    }

    for (int jk = 0; jk < 12; jk++) {
        int j = wv + jk * 8;
        const float* ekrow = EK + ((size_t)b * 96 + j) * KD;
        float a0 = 0.f, a1 = 0.f, a2 = 0.f, a3 = 0.f;
#pragma unroll
        for (int s = 0; s < 4; s++) {
            float4 ek = *(const float4*)(ekrow + col[s]);
#pragma unroll
            for (int c = 0; c < 4; c++) {
                float ekc = ((const float*)&ek)[c];
                float wc  = ((const float*)&w4[s])[c];
                float r0 = __builtin_amdgcn_rcpf(__builtin_fmaf(ekc, ((const float*)&eq[s][0])[c], 1.f));
                float r1 = __builtin_amdgcn_rcpf(__builtin_fmaf(ekc, ((const float*)&eq[s][1])[c], 1.f));
                float r2 = __builtin_amdgcn_rcpf(__builtin_fmaf(ekc, ((const float*)&eq[s][2])[c], 1.f));
                float r3 = __builtin_amdgcn_rcpf(__builtin_fmaf(ekc, ((const float*)&eq[s][3])[c], 1.f));
                a0 = __builtin_fmaf(wc, r0, a0);
                a1 = __builtin_fmaf(wc, r1, a1);
                a2 = __builtin_fmaf(wc, r2, a2);
                a3 = __builtin_fmaf(wc, r3, a3);
            }
        }
#pragma unroll
        for (int off = 32; off; off >>= 1) {
            a0 += __shfl_xor(a0, off);
            a1 += __shfl_xor(a1, off);
            a2 += __shfl_xor(a2, off);
            a3 += __shfl_xor(a3, off);
        }
        if (lane == 0) {
            logit_s[0][j] = -2.f * a0;
            logit_s[1][j] = -2.f * a1;
            logit_s[2][j] = -2.f * a2;
            logit_s[3][j] = -2.f * a3;
        }
    }
    __syncthreads();

    if (wv < 4) {
        float x0 = logit_s[wv][lane];
        float x1 = (lane < 32) ? logit_s[wv][lane + 64] : -1e30f;
        float mx = fmaxf(x0, x1);
#pragma unroll
        for (int off = 32; off; off >>= 1) mx = fmaxf(mx, __shfl_xor(mx, off));
        float e0 = __expf(x0 - mx);
        float e1 = (lane < 32) ? __expf(x1 - mx) : 0.f;
        float sm = e0 + e1;
#pragma unroll
        for (int off = 32; off; off >>= 1) sm += __shfl_xor(sm, off);
        float inv = __fdividef(1.f, sm);
        logit_s[wv][lane] = e0 * inv;
        if (lane < 32) logit_s[wv][lane + 64] = e1 * inv;
    }
    __syncthreads();

    if (tid < 384) {
        int i = tid / 96, j = tid % 96;
        S[((size_t)b * 96 + i0 + i) * 96 + j] = __float2bfloat16(logit_s[i][j]);
    }
}

// =============== h_aT = heT @ S^T  (NT-form, per-b 960x96x96), LDS-free ========
__global__ __launch_bounds__(64) void hat_mfma(
    const __hip_bfloat16* __restrict__ heT, const __hip_bfloat16* __restrict__ S,
    float* __restrict__ h_aT) {
    int b = blockIdx.x / 60;
    int d0 = (blockIdx.x % 60) * 16;
    int lane = threadIdx.x, lq = lane >> 4, lr = lane & 15;
    const char* Ab = (const char*)heT + ((size_t)b * 960 + d0) * 192;
    const char* Bb = (const char*)S + (size_t)b * 96 * 192;
    f32x4 acc[6] = {};
#pragma unroll
    for (int kt = 0; kt < 3; kt++) {
        bf16x8 a = *(const bf16x8*)(Ab + (size_t)lr * 192 + kt * 64 + lq * 16);
#pragma unroll
        for (int ni = 0; ni < 6; ni++) {
            bf16x8 bf = *(const bf16x8*)(Bb + (size_t)(ni * 16 + lr) * 192 + kt * 64 + lq * 16);
            acc[ni] = MFMA_16x16x32_BF16(a, bf, acc[ni], 0, 0, 0);
        }
    }
#pragma unroll
    for (int ni = 0; ni < 6; ni++)
#pragma unroll
        for (int reg = 0; reg < 4; reg++)
            h_aT[((size_t)b * 960 + d0 + lq * 4 + reg) * 96 + ni * 16 + lr] = acc[ni][reg];
}

// =============== temporal decay + dense-interp (fused, transposed space) =======
__global__ __launch_bounds__(128) void decayv_kernel(
    const float* __restrict__ h_aT, const float* __restrict__ MT,
    const float* __restrict__ DFT, const float* __restrict__ W_td,
    const float* __restrict__ b_td, float* __restrict__ h_rT,
    float* __restrict__ v) {
    __shared__ float red[6];
    int b = blockIdx.x / 960, kd = blockIdx.x % 960;
    int t = threadIdx.x;
    int lane = t & 63, wv = t >> 6;
    int d = kd % 96;
    float p0 = 0.f, p1 = 0.f, p2 = 0.f;
    if (t < 96) {
        const float* har = h_aT + ((size_t)b * 960 + kd) * 96;
        float ha = har[t];
        float m  = MT[((size_t)b * 96 + d) * 96 + t];
        float df = DFT[((size_t)b * 96 + d) * 96 + t];
        float g  = __expf(-fmaxf(df * W_td[kd] + b_td[kd], 0.f));
        int tsrc = t - (int)df + 1;
        float hf = har[tsrc];
        float hr = m * ha + (1.f - m) * (g * hf + (1.f - g) * ha);
        h_rT[((size_t)b * 960 + kd) * 96 + t] = hr;
        float p  = 3.f * (t + 1) * (1.f / 96.f);
        float w0 = 1.f - fabsf(p - 1.f) * (1.f / 3.f);
        float w1 = 1.f - fabsf(p - 2.f) * (1.f / 3.f);
        float w2 = 1.f - fabsf(p - 3.f) * (1.f / 3.f);
        p0 = w0 * w0 * hr; p1 = w1 * w1 * hr; p2 = w2 * w2 * hr;
    }
#pragma unroll
    for (int off = 32; off; off >>= 1) {
        p0 += __shfl_down(p0, off);
        p1 += __shfl_down(p1, off);
        p2 += __shfl_down(p2, off);
    }
    if (lane == 0) { red[wv * 3 + 0] = p0; red[wv * 3 + 1] = p1; red[wv * 3 + 2] = p2; }
    __syncthreads();
    if (t == 0) {
        float* vp = v + (size_t)b * 2880 + kd * 3;
        vp[0] = red[0] + red[3];
        vp[1] = red[1] + red[4];
        vp[2] = red[2] + red[5];
    }
}

// =============== imputation (reads h_rT coalesced, scattered write) ============
__global__ __launch_bounds__(128) void imput_kernel(
    const float* __restrict__ h_rT, const float* __restrict__ W_imp,
    const float* __restrict__ b_imp, float* __restrict__ imput) {
    int b = blockIdx.x / 96, d = blockIdx.x % 96;
    int t = threadIdx.x;
    if (t >= 96) return;
    float s = b_imp[d];
#pragma unroll
    for (int k = 0; k < 10; k++)
        s += W_imp[d * KD + k * 96 + d] * h_rT[((size_t)b * 960 + k * 96 + d) * 96 + t];
    imput[((size_t)b * 96 + t) * 96 + d] = s;
}

// =============== final FC ======================================================
__global__ __launch_bounds__(64) void fc_kernel(
    const float* __restrict__ v, const float* __restrict__ W_fc,
    const float* __restrict__ b_fc, float* __restrict__ out) {
    int b = blockIdx.x / 10, o = blockIdx.x % 10;
    int lane = threadIdx.x;
    const float* vp = v + (size_t)b * 2880;
    const float* wp = W_fc + (size_t)o * 2880;
    float s = 0.f;
    for (int j = lane; j < 2880; j += 64) s += vp[j] * wp[j];
#pragma unroll
    for (int off = 32; off; off >>= 1) s += __shfl_down(s, off);
    if (lane == 0) out[b * 10 + o] = s + b_fc[o];
}

extern "C" void kernel_launch(void* const* d_in, const int* in_sizes, int n_in,
                              void* d_out, int out_size, void* d_ws, size_t ws_size,
                              hipStream_t stream) {
    const float* X    = (const float*)d_in[0];
    const float* M    = (const float*)d_in[1];
    const float* DF   = (const float*)d_in[2];
    const float* W_e  = (const float*)d_in[3];
    const float* b_e  = (const float*)d_in[4];
    const float* pos  = (const float*)d_in[5];
    const float* W_a  = (const float*)d_in[6];
    const float* V_a  = (const float*)d_in[7];
    const float* w_a  = (const float*)d_in[8];
    const float* W_td = (const float*)d_in[9];
    const float* b_td = (const float*)d_in[10];
    const float* W_imp= (const float*)d_in[11];
    const float* b_imp= (const float*)d_in[12];
    const float* W_fc = (const float*)d_in[13];
    const float* b_fc = (const float*)d_in[14];

    float* out   = (float*)d_out;         // (16,10)
    float* imput = (float*)d_out + 160;   // (16,96,96)

    char* w = (char*)d_ws;
    __hip_bfloat16* inpb = (__hip_bfloat16*)(w);             //   983,040
    __hip_bfloat16* Web  = (__hip_bfloat16*)(w + 983040);    //   614,400
    __hip_bfloat16* Wab  = (__hip_bfloat16*)(w + 1597440);   // 1,843,200
    __hip_bfloat16* Vab  = (__hip_bfloat16*)(w + 3440640);   // 1,843,200
    __hip_bfloat16* heb  = (__hip_bfloat16*)(w + 5283840);   // 2,949,120
    __hip_bfloat16* heT  = (__hip_bfloat16*)(w + 8232960);   // 2,949,120
    __hip_bfloat16* Sp   = (__hip_bfloat16*)(w + 11182080);  //   294,912
    float* MT   = (float*)(w + 11476992);                    //   589,824
    float* DFT  = (float*)(w + 12066816);                    //   589,824
    float* EK   = (float*)(w + 12656640);                    // 5,898,240
    float* EQ   = (float*)(w + 18554880);                    // 5,898,240
    float* h_aT = EK;    // EK dead after attn
    float* h_rT = EQ;    // EQ dead after attn
    float* vv   = (float*)(w + 24453120);                    //   184,320

    prep_kernel<<<11472, 256, 0, stream>>>(X, M, DF, W_e, W_a, V_a,
                                           inpb, Web, Wab, Vab, MT, DFT);
    embed_mfma<<<dim3(15, 48), 256, 0, stream>>>(inpb, Web, b_e, pos, heb, heT);
    kq_mfma<<<dim3(15, 48), 256, 0, stream>>>(heb, Wab, Vab, EK, EQ);
    attn_kernel<<<NB * 24, 512, 0, stream>>>(EK, EQ, w_a, Sp);
    hat_mfma<<<NB * 60, 64, 0, stream>>>(heT, Sp, h_aT);
    decayv_kernel<<<NB * 960, 128, 0, stream>>>(h_aT, MT, DFT, W_td, b_td, h_rT, vv);
    imput_kernel<<<NB * 96, 128, 0, stream>>>(h_rT, W_imp, b_imp, imput);
    fc_kernel<<<160, 64, 0, stream>>>(vv, W_fc, b_fc, out);
}

// Round 8
// 94.186 us; speedup vs baseline: 1.4394x; 1.0528x over previous
//
#include <hip/hip_runtime.h>
#include <hip/hip_bf16.h>

#define KD 960
#define BT 1536   // 16*96
#define NB 16

typedef __attribute__((ext_vector_type(8))) short bf16x8;
typedef __attribute__((ext_vector_type(4))) float f32x4;

#define MFMA_16x16x32_BF16 __builtin_amdgcn_mfma_f32_16x16x32_bf16

// =============== fused prep: bf16 casts, pads, transposes ===============
__global__ __launch_bounds__(256) void prep_kernel(
    const float* __restrict__ X, const float* __restrict__ M,
    const float* __restrict__ DF, const float* __restrict__ W_e,
    const float* __restrict__ W_a, const float* __restrict__ V_a,
    __hip_bfloat16* __restrict__ inpb, __hip_bfloat16* __restrict__ Web,
    __hip_bfloat16* __restrict__ Wab, __hip_bfloat16* __restrict__ Vab,
    float* __restrict__ MT, float* __restrict__ DFT) {
    int idx = blockIdx.x * 256 + threadIdx.x;
    if (idx < 491520) {               // inp = [X,M,DF,0pad] as (BT,320) bf16
        int m = idx / 320, j = idx % 320;
        float v = 0.f;
        if (j < 96)       v = X[m * 96 + j];
        else if (j < 192) v = M[m * 96 + (j - 96)];
        else if (j < 288) v = DF[m * 96 + (j - 192)];
        inpb[idx] = __float2bfloat16(v);
        return;
    }
    idx -= 491520;
    if (idx < 307200) {               // W_e (960,288) -> (960,320) bf16
        int r = idx / 320, c = idx % 320;
        Web[idx] = __float2bfloat16(c < 288 ? W_e[r * 288 + c] : 0.f);
        return;
    }
    idx -= 307200;
    if (idx < 921600) { Wab[idx] = __float2bfloat16(W_a[idx]); return; }
    idx -= 921600;
    if (idx < 921600) { Vab[idx] = __float2bfloat16(V_a[idx]); return; }
    idx -= 921600;
    if (idx < 147456) {               // MT[b][d][t] = M[b][t][d]
        int b = idx / 9216, r = idx % 9216, d = r / 96, t = r % 96;
        MT[idx] = M[(b * 96 + t) * 96 + d];
        return;
    }
    idx -= 147456;
    if (idx < 147456) {
        int b = idx / 9216, r = idx % 9216, d = r / 96, t = r % 96;
        DFT[idx] = DF[(b * 96 + t) * 96 + d];
    }
}

// =============== MFMA staging helpers (m97 pattern, XOR-swizzled) ===============
__device__ __forceinline__ void stage64(const char* gRow0, int ldbytes,
                                        char* ldsTile, int wv, int lane) {
#pragma unroll
    for (int rd = 0; rd < 2; rd++) {
        int c  = rd * 256 + wv * 64 + lane;
        int r  = c >> 3;
        int sl = c & 7;
        int ss = sl ^ (r & 7);
        const char* g = gRow0 + (size_t)r * ldbytes + ss * 16;
        __builtin_amdgcn_global_load_lds((const void*)g,
            (void*)(ldsTile + rd * 4096 + wv * 1024), 16, 0, 0);
    }
}
__device__ __forceinline__ void stage32(const char* gRow0, int ldbytes,
                                        char* ldsTile, int tid, int wv) {
    int r  = tid >> 3;
    int sl = tid & 7;
    int ss = sl ^ (r & 7);
    const char* g = gRow0 + (size_t)r * ldbytes + ss * 16;
    __builtin_amdgcn_global_load_lds((const void*)g,
        (void*)(ldsTile + wv * 1024), 16, 0, 0);
}
__device__ __forceinline__ bf16x8 ldfrag(const char* lds, int row, int slot) {
    int ss = slot ^ (row & 7);
    return *(const bf16x8*)(lds + row * 128 + ss * 16);
}

// =============== embed: 32x64 tiles, K=320; writes heb + transposed heT ========
__global__ __launch_bounds__(256) void embed_mfma(
    const __hip_bfloat16* __restrict__ A, const __hip_bfloat16* __restrict__ Bw,
    const float* __restrict__ b_e, const float* __restrict__ pos,
    __hip_bfloat16* __restrict__ heb, __hip_bfloat16* __restrict__ heT) {
    __shared__ __align__(16) char lds[12288];
    char* As = lds; char* Bs = lds + 4096;
    int tid = threadIdx.x, lane = tid & 63, wv = tid >> 6;
    int lq = lane >> 4, lr = lane & 15;
    int m0 = blockIdx.y * 32, n0 = blockIdx.x * 64;
    int wm = (wv >> 1) * 16, wn = (wv & 1) * 32;
    f32x4 acc[2] = {};
    for (int kt = 0; kt < 5; kt++) {
        int k0b = kt * 128;
        stage32((const char*)A + (size_t)m0 * 640 + k0b, 640, As, tid, wv);
        stage64((const char*)Bw + (size_t)n0 * 640 + k0b, 640, Bs, wv, lane);
        __syncthreads();
#pragma unroll
        for (int h = 0; h < 2; h++) {
            bf16x8 a  = ldfrag(As, wm + lr, h * 4 + lq);
            bf16x8 b0 = ldfrag(Bs, wn + lr,      h * 4 + lq);
            bf16x8 b1 = ldfrag(Bs, wn + 16 + lr, h * 4 + lq);
            acc[0] = MFMA_16x16x32_BF16(a, b0, acc[0], 0, 0, 0);
            acc[1] = MFMA_16x16x32_BF16(a, b1, acc[1], 0, 0, 0);
        }
        __syncthreads();
    }
    int mbase = m0 + wm + lq * 4;
    int b = mbase / 96, t0 = mbase % 96;
#pragma unroll
    for (int ni = 0; ni < 2; ni++) {
        int n = n0 + wn + ni * 16 + lr;
        float bn = b_e[n];
        ushort4 pk;
#pragma unroll
        for (int reg = 0; reg < 4; reg++) {
            int t = t0 + reg;
            float x = acc[ni][reg] + bn + pos[t * KD + n];
            x = x > 0.f ? x : (__expf(x) - 1.f);
            __hip_bfloat16 hv = __float2bfloat16(x);
            heb[(size_t)(mbase + reg) * KD + n] = hv;
            ((unsigned short*)&pk)[reg] = *(unsigned short*)&hv;
        }
        *(ushort4*)((char*)heT + (((size_t)b * 960 + n) * 96 + t0) * 2) = pk;
    }
}

// =============== fused key/qry GEMM; epilogue stores EK=e^{2k}, EQ=e^{2q} ======
__global__ __launch_bounds__(256) void kq_mfma(
    const __hip_bfloat16* __restrict__ A, const __hip_bfloat16* __restrict__ B1,
    const __hip_bfloat16* __restrict__ B2,
    float* __restrict__ EK, float* __restrict__ EQ) {
    __shared__ __align__(16) char lds[20480];
    char* As = lds; char* B1s = lds + 4096; char* B2s = lds + 12288;
    int tid = threadIdx.x, lane = tid & 63, wv = tid >> 6;
    int lq = lane >> 4, lr = lane & 15;
    int m0 = blockIdx.y * 32, n0 = blockIdx.x * 64;
    int wm = (wv >> 1) * 16, wn = (wv & 1) * 32;
    f32x4 aK[2] = {}, aQ[2] = {};
    for (int kt = 0; kt < 15; kt++) {
        int k0b = kt * 128;
        stage32((const char*)A + (size_t)m0 * 1920 + k0b, 1920, As, tid, wv);
        stage64((const char*)B1 + (size_t)n0 * 1920 + k0b, 1920, B1s, wv, lane);
        stage64((const char*)B2 + (size_t)n0 * 1920 + k0b, 1920, B2s, wv, lane);
        __syncthreads();
#pragma unroll
        for (int h = 0; h < 2; h++) {
            bf16x8 a   = ldfrag(As,  wm + lr, h * 4 + lq);
            bf16x8 b10 = ldfrag(B1s, wn + lr,      h * 4 + lq);
            bf16x8 b11 = ldfrag(B1s, wn + 16 + lr, h * 4 + lq);
            bf16x8 b20 = ldfrag(B2s, wn + lr,      h * 4 + lq);
            bf16x8 b21 = ldfrag(B2s, wn + 16 + lr, h * 4 + lq);
            aK[0] = MFMA_16x16x32_BF16(a, b10, aK[0], 0, 0, 0);
            aK[1] = MFMA_16x16x32_BF16(a, b11, aK[1], 0, 0, 0);
            aQ[0] = MFMA_16x16x32_BF16(a, b20, aQ[0], 0, 0, 0);
            aQ[1] = MFMA_16x16x32_BF16(a, b21, aQ[1], 0, 0, 0);
        }
        __syncthreads();
    }
    const float c2 = 2.885390081777927f;  // 2*log2(e)
    int mbase = m0 + wm + lq * 4;
#pragma unroll
    for (int ni = 0; ni < 2; ni++) {
        int n = n0 + wn + ni * 16 + lr;
#pragma unroll
        for (int reg = 0; reg < 4; reg++) {
            float ek = exp2f(fminf(fmaxf(aK[ni][reg] * c2, -80.f), 80.f));
            float eq = exp2f(fminf(fmaxf(aQ[ni][reg] * c2, -80.f), 80.f));
            EK[(size_t)(mbase + reg) * KD + n] = ek;
            EQ[(size_t)(mbase + reg) * KD + n] = eq;
        }
    }
}

// =============== attention logits + softmax -> S (bf16 probs) ==================
// logit = -2*sum_d w_d*rcp(EK_jd*EQ_id+1)   (softmax-equiv; tanh factored)
// block (b, 3 i-rows), 512 thr = 8 waves; grid 512 = exactly 2 blocks/CU.
// wave owns j = wv+8k (12 iters); lane owns fixed float4 d-slices.
__global__ __launch_bounds__(512) void attn_kernel(
    const float* __restrict__ EK, const float* __restrict__ EQ,
    const float* __restrict__ w_a, __hip_bfloat16* __restrict__ S) {
    __shared__ float logit_s[3][96];
    int bid = blockIdx.x;
    int b = bid & 15, i0 = (bid >> 4) * 3;
    int tid = threadIdx.x;
    int lane = tid & 63, wv = tid >> 6;
    bool act = lane < 60;

    int col[4];
    float4 w4[4], eq[4][3];
#pragma unroll
    for (int s = 0; s < 4; s++) {
        col[s] = act ? s * 240 + lane * 4 : 0;
        if (act) w4[s] = *(const float4*)(w_a + s * 240 + lane * 4);
        else     w4[s] = float4{0.f, 0.f, 0.f, 0.f};
#pragma unroll
        for (int i = 0; i < 3; i++)
            eq[s][i] = *(const float4*)(EQ + ((size_t)b * 96 + i0 + i) * KD + col[s]);
    }

    for (int jk = 0; jk < 12; jk++) {
        int j = wv + jk * 8;
        const float* ekrow = EK + ((size_t)b * 96 + j) * KD;
        float a0 = 0.f, a1 = 0.f, a2 = 0.f;
#pragma unroll
        for (int s = 0; s < 4; s++) {
            float4 ek = *(const float4*)(ekrow + col[s]);
#pragma unroll
            for (int c = 0; c < 4; c++) {
                float ekc = ((const float*)&ek)[c];
                float wc  = ((const float*)&w4[s])[c];
                float r0 = __builtin_amdgcn_rcpf(__builtin_fmaf(ekc, ((const float*)&eq[s][0])[c], 1.f));
                float r1 = __builtin_amdgcn_rcpf(__builtin_fmaf(ekc, ((const float*)&eq[s][1])[c], 1.f));
                float r2 = __builtin_amdgcn_rcpf(__builtin_fmaf(ekc, ((const float*)&eq[s][2])[c], 1.f));
                a0 = __builtin_fmaf(wc, r0, a0);
                a1 = __builtin_fmaf(wc, r1, a1);
                a2 = __builtin_fmaf(wc, r2, a2);
            }
        }
#pragma unroll
        for (int off = 32; off; off >>= 1) {
            a0 += __shfl_xor(a0, off);
            a1 += __shfl_xor(a1, off);
            a2 += __shfl_xor(a2, off);
        }
        if (lane == 0) {
            logit_s[0][j] = -2.f * a0;
            logit_s[1][j] = -2.f * a1;
            logit_s[2][j] = -2.f * a2;
        }
    }
    __syncthreads();

    if (wv < 3) {
        float x0 = logit_s[wv][lane];
        float x1 = (lane < 32) ? logit_s[wv][lane + 64] : -1e30f;
        float mx = fmaxf(x0, x1);
#pragma unroll
        for (int off = 32; off; off >>= 1) mx = fmaxf(mx, __shfl_xor(mx, off));
        float e0 = __expf(x0 - mx);
        float e1 = (lane < 32) ? __expf(x1 - mx) : 0.f;
        float sm = e0 + e1;
#pragma unroll
        for (int off = 32; off; off >>= 1) sm += __shfl_xor(sm, off);
        float inv = __fdividef(1.f, sm);
        logit_s[wv][lane] = e0 * inv;
        if (lane < 32) logit_s[wv][lane + 64] = e1 * inv;
    }
    __syncthreads();

    if (tid < 288) {
        int i = tid / 96, j = tid % 96;
        S[((size_t)b * 96 + i0 + i) * 96 + j] = __float2bfloat16(logit_s[i][j]);
    }
}

// =============== fused: h_aT tile MFMA -> decay -> h_rT + dense-interp =========
// one wave per (b, 16 kd-rows). h_aT lives only in LDS.
__global__ __launch_bounds__(64) void hatdecay_kernel(
    const __hip_bfloat16* __restrict__ heT, const __hip_bfloat16* __restrict__ S,
    const float* __restrict__ MT, const float* __restrict__ DFT,
    const float* __restrict__ W_td, const float* __restrict__ b_td,
    float* __restrict__ h_rT, float* __restrict__ v) {
    __shared__ float ha_s[16][97];
    __shared__ float hr_s[16][97];
    int b = blockIdx.x / 60;
    int d0 = (blockIdx.x % 60) * 16;
    int lane = threadIdx.x, lq = lane >> 4, lr = lane & 15;

    // --- MFMA: h_aT[16][96] = heT[d0:d0+16][:] @ S^T ---
    const char* Ab = (const char*)heT + ((size_t)b * 960 + d0) * 192;
    const char* Bb = (const char*)S + (size_t)b * 96 * 192;
    f32x4 acc[6] = {};
#pragma unroll
    for (int kt = 0; kt < 3; kt++) {
        bf16x8 a = *(const bf16x8*)(Ab + (size_t)lr * 192 + kt * 64 + lq * 16);
#pragma unroll
        for (int ni = 0; ni < 6; ni++) {
            bf16x8 bf = *(const bf16x8*)(Bb + (size_t)(ni * 16 + lr) * 192 + kt * 64 + lq * 16);
            acc[ni] = MFMA_16x16x32_BF16(a, bf, acc[ni], 0, 0, 0);
        }
    }
#pragma unroll
    for (int ni = 0; ni < 6; ni++)
#pragma unroll
        for (int reg = 0; reg < 4; reg++)
            ha_s[lq * 4 + reg][ni * 16 + lr] = acc[ni][reg];
    __syncthreads();

    // --- decay per row (t = lane, lane+64) ---
    int d_base = d0 % 96;
#pragma unroll 4
    for (int rr = 0; rr < 16; rr++) {
        int kd = d0 + rr;
        int dd = d_base + rr;
        float wtd = W_td[kd], btd = b_td[kd];
        const float* mrow  = MT  + ((size_t)b * 96 + dd) * 96;
        const float* dfrow = DFT + ((size_t)b * 96 + dd) * 96;
        float* hrow = h_rT + ((size_t)b * 960 + kd) * 96;
#pragma unroll
        for (int half = 0; half < 2; half++) {
            int t = half * 64 + lane;
            if (t < 96) {
                float ha = ha_s[rr][t];
                float m  = mrow[t];
                float df = dfrow[t];
                float g  = __expf(-fmaxf(__builtin_fmaf(df, wtd, btd), 0.f));
                int tsrc = t - (int)df + 1;
                float hf = ha_s[rr][tsrc];
                float hr = m * ha + (1.f - m) * (g * hf + (1.f - g) * ha);
                hrow[t] = hr;
                hr_s[rr][t] = hr;
            }
        }
    }
    __syncthreads();

    // --- dense interpolation: v[b][kd][f] = sum_t w2(f,t)*hr[kd][t] ---
    if (lane < 48) {
        int rr = lane & 15, f = lane >> 4;
        float fp1 = 1.f + (float)f;
        float a = 0.f;
        for (int t = 0; t < 96; t++) {
            float p  = (float)(3 * (t + 1)) * (1.f / 96.f);
            float wf = 1.f - fabsf(p - fp1) * (1.f / 3.f);
            a = __builtin_fmaf(wf * wf, hr_s[rr][t], a);
        }
        v[(size_t)b * 2880 + (d0 + rr) * 3 + f] = a;
    }
}

// =============== imputation (reads h_rT coalesced, scattered write) ============
__global__ __launch_bounds__(128) void imput_kernel(
    const float* __restrict__ h_rT, const float* __restrict__ W_imp,
    const float* __restrict__ b_imp, float* __restrict__ imput) {
    int b = blockIdx.x / 96, d = blockIdx.x % 96;
    int t = threadIdx.x;
    if (t >= 96) return;
    float s = b_imp[d];
#pragma unroll
    for (int k = 0; k < 10; k++)
        s += W_imp[d * KD + k * 96 + d] * h_rT[((size_t)b * 960 + k * 96 + d) * 96 + t];
    imput[((size_t)b * 96 + t) * 96 + d] = s;
}

// =============== final FC ======================================================
__global__ __launch_bounds__(64) void fc_kernel(
    const float* __restrict__ v, const float* __restrict__ W_fc,
    const float* __restrict__ b_fc, float* __restrict__ out) {
    int b = blockIdx.x / 10, o = blockIdx.x % 10;
    int lane = threadIdx.x;
    const float* vp = v + (size_t)b * 2880;
    const float* wp = W_fc + (size_t)o * 2880;
    float s = 0.f;
    for (int j = lane; j < 2880; j += 64) s += vp[j] * wp[j];
#pragma unroll
    for (int off = 32; off; off >>= 1) s += __shfl_down(s, off);
    if (lane == 0) out[b * 10 + o] = s + b_fc[o];
}

extern "C" void kernel_launch(void* const* d_in, const int* in_sizes, int n_in,
                              void* d_out, int out_size, void* d_ws, size_t ws_size,
                              hipStream_t stream) {
    const float* X    = (const float*)d_in[0];
    const float* M    = (const float*)d_in[1];
    const float* DF   = (const float*)d_in[2];
    const float* W_e  = (const float*)d_in[3];
    const float* b_e  = (const float*)d_in[4];
    const float* pos  = (const float*)d_in[5];
    const float* W_a  = (const float*)d_in[6];
    const float* V_a  = (const float*)d_in[7];
    const float* w_a  = (const float*)d_in[8];
    const float* W_td = (const float*)d_in[9];
    const float* b_td = (const float*)d_in[10];
    const float* W_imp= (const float*)d_in[11];
    const float* b_imp= (const float*)d_in[12];
    const float* W_fc = (const float*)d_in[13];
    const float* b_fc = (const float*)d_in[14];

    float* out   = (float*)d_out;         // (16,10)
    float* imput = (float*)d_out + 160;   // (16,96,96)

    char* w = (char*)d_ws;
    __hip_bfloat16* inpb = (__hip_bfloat16*)(w);             //   983,040
    __hip_bfloat16* Web  = (__hip_bfloat16*)(w + 983040);    //   614,400
    __hip_bfloat16* Wab  = (__hip_bfloat16*)(w + 1597440);   // 1,843,200
    __hip_bfloat16* Vab  = (__hip_bfloat16*)(w + 3440640);   // 1,843,200
    __hip_bfloat16* heb  = (__hip_bfloat16*)(w + 5283840);   // 2,949,120
    __hip_bfloat16* heT  = (__hip_bfloat16*)(w + 8232960);   // 2,949,120
    __hip_bfloat16* Sp   = (__hip_bfloat16*)(w + 11182080);  //   294,912
    float* MT   = (float*)(w + 11476992);                    //   589,824
    float* DFT  = (float*)(w + 12066816);                    //   589,824
    float* EK   = (float*)(w + 12656640);                    // 5,898,240
    float* EQ   = (float*)(w + 18554880);                    // 5,898,240
    float* h_rT = EQ;    // EQ dead after attn
    float* vv   = (float*)(w + 24453120);                    //   184,320

    prep_kernel<<<11472, 256, 0, stream>>>(X, M, DF, W_e, W_a, V_a,
                                           inpb, Web, Wab, Vab, MT, DFT);
    embed_mfma<<<dim3(15, 48), 256, 0, stream>>>(inpb, Web, b_e, pos, heb, heT);
    kq_mfma<<<dim3(15, 48), 256, 0, stream>>>(heb, Wab, Vab, EK, EQ);
    attn_kernel<<<NB * 32, 512, 0, stream>>>(EK, EQ, w_a, Sp);
    hatdecay_kernel<<<NB * 60, 64, 0, stream>>>(heT, Sp, MT, DFT, W_td, b_td, h_rT, vv);
    imput_kernel<<<NB * 96, 128, 0, stream>>>(h_rT, W_imp, b_imp, imput);
    fc_kernel<<<160, 64, 0, stream>>>(vv, W_fc, b_fc, out);
}